// Round 3
// baseline (650.144 us; speedup 1.0000x reference)
//
#include <hip/hip_runtime.h>

#define B_ 4
#define D_ 1024
#define N_ 2048
#define H_ 16
#define HD_ 64

typedef unsigned short u16;
typedef __attribute__((ext_vector_type(8))) short bf16x8;
typedef __attribute__((ext_vector_type(4))) float f32x4;
typedef __attribute__((ext_vector_type(8))) unsigned short ushort8v;
typedef __attribute__((ext_vector_type(4))) unsigned short ushort4v;

__device__ __forceinline__ u16 f2bf(float f) {
  unsigned u = __builtin_bit_cast(unsigned, f);
  u += 0x7FFFu + ((u >> 16) & 1u);   // RNE
  return (u16)(u >> 16);
}

// ---------------------------------------------------------------------------
// Cast 4 weight matrices [D][D] fp32 -> bf16 (layout preserved).
// ---------------------------------------------------------------------------
__global__ __launch_bounds__(256) void convert_w4(
    const float* __restrict__ w0, const float* __restrict__ w1,
    const float* __restrict__ w2, const float* __restrict__ w3,
    u16* __restrict__ o0, u16* __restrict__ o1,
    u16* __restrict__ o2, u16* __restrict__ o3) {
  const int z = blockIdx.z;
  const float* s = (z == 0) ? w0 : (z == 1) ? w1 : (z == 2) ? w2 : w3;
  u16*         o = (z == 0) ? o0 : (z == 1) ? o1 : (z == 2) ? o2 : o3;
  const int idx = (blockIdx.x * 256 + threadIdx.x) * 4;
  const float4 v = *(const float4*)&s[idx];
  ushort4v u;
  u[0] = f2bf(v.x); u[1] = f2bf(v.y); u[2] = f2bf(v.z); u[3] = f2bf(v.w);
  *(ushort4v*)&o[idx] = u;
}

// ---------------------------------------------------------------------------
// Transpose+cast: X[b][d][n] fp32 -> Xt[b][n][d] bf16 (K-contiguous B-operand).
// ---------------------------------------------------------------------------
__global__ __launch_bounds__(256) void transpose_cast(
    const float* __restrict__ X, u16* __restrict__ Xt) {
  const int b  = blockIdx.z;
  const int n0 = blockIdx.x * 64;
  const int d0 = blockIdx.y * 64;
  __shared__ float t[64][65];
  const int tid = threadIdx.x;
  const int r   = tid >> 2;
  const int cb  = (tid & 3) * 16;
  const float* __restrict__ Xb = X + (size_t)b * D_ * N_;
  u16* __restrict__ Xtb        = Xt + (size_t)b * N_ * D_;
#pragma unroll
  for (int j = 0; j < 4; ++j) {
    const float4 v = *(const float4*)&Xb[(size_t)(d0 + r) * N_ + n0 + cb + j * 4];
    t[r][cb + j * 4 + 0] = v.x;
    t[r][cb + j * 4 + 1] = v.y;
    t[r][cb + j * 4 + 2] = v.z;
    t[r][cb + j * 4 + 3] = v.w;
  }
  __syncthreads();
  ushort8v lo, hi;
#pragma unroll
  for (int j = 0; j < 8; ++j) lo[j] = f2bf(t[cb + j][r]);
#pragma unroll
  for (int j = 0; j < 8; ++j) hi[j] = f2bf(t[cb + 8 + j][r]);
  *(ushort8v*)&Xtb[(size_t)(n0 + r) * D_ + d0 + cb]     = lo;
  *(ushort8v*)&Xtb[(size_t)(n0 + r) * D_ + d0 + cb + 8] = hi;
}

// ---------------------------------------------------------------------------
// bf16 MFMA projection (m97 structure): C[e,n] = sum_d W[e,d]*Xt[n,d] + b[e].
// 128x128 tile, BK=32, 4 waves 2x2, 4x4 frags of 16x16x32 each.
// ---------------------------------------------------------------------------
__global__ __launch_bounds__(256) void proj_mfma(
    const u16* __restrict__ Wb, const u16* __restrict__ Xt,
    const float* __restrict__ bias, float* __restrict__ Y) {
  const int b  = blockIdx.z;
  const int n0 = blockIdx.x * 128;
  const int e0 = blockIdx.y * 128;
  const u16* __restrict__ Xb = Xt + (size_t)b * N_ * D_;
  float* __restrict__ Yb     = Y + (size_t)b * D_ * N_;

  __shared__ __attribute__((aligned(16))) u16 As[128 * 32];  // [e][k]
  __shared__ __attribute__((aligned(16))) u16 Bs[128 * 32];  // [n][k]

  const int tid  = threadIdx.x;
  const int w    = tid >> 6;
  const int lane = tid & 63;
  const int wm   = (w >> 1) * 64;
  const int wn   = (w & 1) * 64;

  const int srow  = lane >> 2;
  const int skcol = (lane & 3) * 8;
  const int c0    = w * 2;

  const f32x4 z4 = {0.f, 0.f, 0.f, 0.f};
  f32x4 acc[4][4];
#pragma unroll
  for (int i = 0; i < 4; ++i)
#pragma unroll
    for (int j = 0; j < 4; ++j) acc[i][j] = z4;

  for (int k0 = 0; k0 < D_; k0 += 32) {
    __syncthreads();
#pragma unroll
    for (int i = 0; i < 2; ++i) {
      const int c = c0 + i;
      const u16* ga = Wb + (size_t)(e0 + c * 16 + srow) * D_ + k0 + skcol;
      const u16* gb = Xb + (size_t)(n0 + c * 16 + srow) * D_ + k0 + skcol;
      __builtin_amdgcn_global_load_lds(
          (__attribute__((address_space(1))) void*)ga,
          (__attribute__((address_space(3))) void*)(As + c * 512), 16, 0, 0);
      __builtin_amdgcn_global_load_lds(
          (__attribute__((address_space(1))) void*)gb,
          (__attribute__((address_space(3))) void*)(Bs + c * 512), 16, 0, 0);
    }
    __syncthreads();

    bf16x8 af[4], bfr[4];
#pragma unroll
    for (int i = 0; i < 4; ++i)
      af[i] = *(const bf16x8*)&As[(wm + i * 16 + (lane & 15)) * 32 + (lane >> 4) * 8];
#pragma unroll
    for (int j = 0; j < 4; ++j)
      bfr[j] = *(const bf16x8*)&Bs[(wn + j * 16 + (lane & 15)) * 32 + (lane >> 4) * 8];
#pragma unroll
    for (int i = 0; i < 4; ++i)
#pragma unroll
      for (int j = 0; j < 4; ++j)
        acc[i][j] = __builtin_amdgcn_mfma_f32_16x16x32_bf16(af[i], bfr[j], acc[i][j], 0, 0, 0);
  }

  const int col = lane & 15;
  const int rg  = (lane >> 4) * 4;
#pragma unroll
  for (int i = 0; i < 4; ++i) {
#pragma unroll
    for (int r = 0; r < 4; ++r) {
      const int e    = e0 + wm + i * 16 + rg + r;
      const float be = bias[e];
      float* yr = &Yb[(size_t)e * N_ + n0 + wn + col];
#pragma unroll
      for (int j = 0; j < 4; ++j) yr[j * 16] = acc[i][j][r] + be;
    }
  }
}

// ---------------------------------------------------------------------------
// repack_nh: P[b][e][n] fp32 (e = hd*16 + h) -> Out[b][h][n][hd] bf16.
// LDS 64x64 transpose per (b, h, n-tile).
// ---------------------------------------------------------------------------
__global__ __launch_bounds__(256) void repack_nh(
    const float* __restrict__ P, u16* __restrict__ Out) {
  const int b  = blockIdx.z;
  const int h  = blockIdx.y;
  const int n0 = blockIdx.x * 64;
  __shared__ float t[64][65];
  const int tid = threadIdx.x;
  const int r   = tid >> 2;
  const int cb  = (tid & 3) * 16;
  const float* __restrict__ Pr = P + ((size_t)b * D_ + (size_t)r * H_ + h) * N_;
#pragma unroll
  for (int j = 0; j < 4; ++j) {
    const float4 v = *(const float4*)&Pr[n0 + cb + j * 4];
    t[r][cb + j * 4 + 0] = v.x;
    t[r][cb + j * 4 + 1] = v.y;
    t[r][cb + j * 4 + 2] = v.z;
    t[r][cb + j * 4 + 3] = v.w;
  }
  __syncthreads();
  u16* __restrict__ Ob = Out + (((size_t)(b * H_ + h)) * N_ + n0 + r) * HD_;
  ushort8v lo, hi;
#pragma unroll
  for (int j = 0; j < 8; ++j) lo[j] = f2bf(t[cb + j][r]);
#pragma unroll
  for (int j = 0; j < 8; ++j) hi[j] = f2bf(t[cb + 8 + j][r]);
  *(ushort8v*)&Ob[cb]     = lo;
  *(ushort8v*)&Ob[cb + 8] = hi;
}

// ---------------------------------------------------------------------------
// repack_vh: P[b][e][n] fp32 -> Out[b][h][hd][n] bf16 (row permute + cast).
// ---------------------------------------------------------------------------
__global__ __launch_bounds__(256) void repack_vh(
    const float* __restrict__ P, u16* __restrict__ Out) {
  const int b  = blockIdx.z;
  const int e  = blockIdx.y;
  const int n0 = blockIdx.x * 1024 + threadIdx.x * 4;
  const int h  = e & 15;
  const int hd = e >> 4;
  const float4 v = *(const float4*)&P[((size_t)b * D_ + e) * N_ + n0];
  ushort4v u;
  u[0] = f2bf(v.x); u[1] = f2bf(v.y); u[2] = f2bf(v.z); u[3] = f2bf(v.w);
  *(ushort4v*)&Out[(((size_t)(b * H_ + h)) * HD_ + hd) * N_ + n0] = u;
}

// ---------------------------------------------------------------------------
// repack_oh: Oh[b][h][n][hd] bf16 -> Xt[b][n][d = hd*16+h] bf16.
// Block per (n, b); thread t handles d = (t>>2)*16 + (t&3)*4 .. +3.
// ---------------------------------------------------------------------------
__global__ __launch_bounds__(256) void repack_oh(
    const u16* __restrict__ Oh, u16* __restrict__ Xt) {
  const int n  = blockIdx.x;
  const int b  = blockIdx.y;
  const int t  = threadIdx.x;
  const int hd = t >> 2;
  const int h0 = (t & 3) * 4;
  ushort4v u;
#pragma unroll
  for (int i = 0; i < 4; ++i)
    u[i] = Oh[(((size_t)(b * H_ + h0 + i)) * N_ + n) * HD_ + hd];
  *(ushort4v*)&Xt[((size_t)b * N_ + n) * D_ + hd * 16 + h0] = u;
}

// ---------------------------------------------------------------------------
// attn_mfma: per (b,h): S = Q K^T * 0.125, online softmax, O = P V.
// Qh/Kh: [B][H][N][64] bf16; Vh: [B][H][64][N] bf16; Oh: [B][H][N][64] bf16.
// Block = 64 q-rows (4 waves x 16), KV tiles of 64, reg-staged dbuf K/V in
// LDS with pad-72 rows (<=2-way conflicts), per-wave P tile in LDS.
// MFMA frag convention (canonical gfx950): A: lane(g=l>>4,c=l&15) holds
// A[row=c][k=g*8..+7]; B: B[k=g*8..+7][col=c]; D: D[g*4+r][c].
// ---------------------------------------------------------------------------
__global__ __launch_bounds__(256) void attn_mfma(
    const u16* __restrict__ Qh, const u16* __restrict__ Kh,
    const u16* __restrict__ Vh, u16* __restrict__ Oh) {
  const int n0 = blockIdx.x * 64;
  const int h  = blockIdx.y;
  const int b  = blockIdx.z;
  const int tid  = threadIdx.x;
  const int wv   = tid >> 6;
  const int lane = tid & 63;
  const int g    = lane >> 4;
  const int c    = lane & 15;

  __shared__ __attribute__((aligned(16))) u16 Ks[64 * 72];   // [m][hd] pad72
  __shared__ __attribute__((aligned(16))) u16 Vs[64 * 72];   // [hd][m] pad72
  __shared__ __attribute__((aligned(16))) u16 ps[4][16 * 72]; // per-wave P

  const size_t bh = (size_t)(b * H_ + h);
  const u16* __restrict__ Qbase = Qh + bh * N_ * HD_;
  const char* __restrict__ Kc   = (const char*)(Kh + bh * N_ * HD_);
  const char* __restrict__ Vc0  = (const char*)(Vh + bh * HD_ * N_);

  // Q fragments, hoisted for the whole block (row = n0 + wv*16 + c)
  bf16x8 qa[2];
  {
    const u16* qrow = Qbase + (size_t)(n0 + wv * 16 + c) * HD_ + g * 8;
    qa[0] = *(const bf16x8*)(qrow);
    qa[1] = *(const bf16x8*)(qrow + 32);
  }

  // staging: thread -> row srow (0..63), 32 contiguous bytes at sboff
  const int srow  = tid >> 2;
  const int sboff = (tid & 3) * 32;
  const char* Vc = Vc0 + (size_t)srow * (N_ * 2);
  u16* KsW = Ks + srow * 72 + sboff / 2;
  u16* VsW = Vs + srow * 72 + sboff / 2;

  f32x4 o[4];
  float mold[4], l[4];
#pragma unroll
  for (int jh = 0; jh < 4; ++jh) o[jh] = f32x4{0.f, 0.f, 0.f, 0.f};
#pragma unroll
  for (int r = 0; r < 4; ++r) { mold[r] = -1e30f; l[r] = 0.f; }

  const float sc = 0.125f;  // 1/sqrt(64)

  auto compute = [&]() {
    // ---- S = Q K^T
    f32x4 s[4];
#pragma unroll
    for (int j = 0; j < 4; ++j) s[j] = f32x4{0.f, 0.f, 0.f, 0.f};
#pragma unroll
    for (int ks = 0; ks < 2; ++ks) {
#pragma unroll
      for (int j = 0; j < 4; ++j) {
        const bf16x8 kb = *(const bf16x8*)&Ks[(j * 16 + c) * 72 + ks * 32 + g * 8];
        s[j] = __builtin_amdgcn_mfma_f32_16x16x32_bf16(qa[ks], kb, s[j], 0, 0, 0);
      }
    }
    // ---- online softmax (rows g*4+r live in 16 consecutive lanes g*16..+15)
#pragma unroll
    for (int r = 0; r < 4; ++r) {
      float m_ = fmaxf(fmaxf(s[0][r], s[1][r]), fmaxf(s[2][r], s[3][r])) * sc;
      m_ = fmaxf(m_, __shfl_xor(m_, 1));
      m_ = fmaxf(m_, __shfl_xor(m_, 2));
      m_ = fmaxf(m_, __shfl_xor(m_, 4));
      m_ = fmaxf(m_, __shfl_xor(m_, 8));
      const float mnew = fmaxf(mold[r], m_);
      const float al   = __expf(mold[r] - mnew);
      mold[r] = mnew;
      float ls = 0.f;
#pragma unroll
      for (int j = 0; j < 4; ++j) {
        const float p = __expf(s[j][r] * sc - mnew);
        ps[wv][(g * 4 + r) * 72 + j * 16 + c] = f2bf(p);
        ls += p;
      }
      ls += __shfl_xor(ls, 1);
      ls += __shfl_xor(ls, 2);
      ls += __shfl_xor(ls, 4);
      ls += __shfl_xor(ls, 8);
      l[r] = l[r] * al + ls;
      o[0][r] *= al; o[1][r] *= al; o[2][r] *= al; o[3][r] *= al;
    }
    // ---- O += P V   (same-wave DS ordering: no barrier needed for ps)
#pragma unroll
    for (int ks = 0; ks < 2; ++ks) {
      const bf16x8 pa = *(const bf16x8*)&ps[wv][c * 72 + ks * 32 + g * 8];
#pragma unroll
      for (int jh = 0; jh < 4; ++jh) {
        const bf16x8 vb = *(const bf16x8*)&Vs[(jh * 16 + c) * 72 + ks * 32 + g * 8];
        o[jh] = __builtin_amdgcn_mfma_f32_16x16x32_bf16(pa, vb, o[jh], 0, 0, 0);
      }
    }
  };

  // prologue: load tile 0 into reg set A
  float4 kra[2], vra[2], krb[2], vrb[2];
  {
    const char* kp = Kc + (size_t)srow * 128 + sboff;
    kra[0] = *(const float4*)kp;  kra[1] = *(const float4*)(kp + 16);
    const char* vp = Vc + sboff;
    vra[0] = *(const float4*)vp;  vra[1] = *(const float4*)(vp + 16);
  }

  for (int t = 0; t < N_ / 64; t += 2) {
    // ---- even tile t: stage A, prefetch B (t+1)
    __syncthreads();
    *(float4*)(KsW) = kra[0];  *(float4*)(KsW + 8) = kra[1];
    *(float4*)(VsW) = vra[0];  *(float4*)(VsW + 8) = vra[1];
    {
      const int m1 = (t + 1) * 64;
      const char* kp = Kc + (size_t)(m1 + srow) * 128 + sboff;
      krb[0] = *(const float4*)kp;  krb[1] = *(const float4*)(kp + 16);
      const char* vp = Vc + (size_t)m1 * 2 + sboff;
      vrb[0] = *(const float4*)vp;  vrb[1] = *(const float4*)(vp + 16);
    }
    __syncthreads();
    compute();
    // ---- odd tile t+1: stage B, prefetch A (t+2, wrapped)
    __syncthreads();
    *(float4*)(KsW) = krb[0];  *(float4*)(KsW + 8) = krb[1];
    *(float4*)(VsW) = vrb[0];  *(float4*)(VsW + 8) = vrb[1];
    {
      const int m2 = ((t + 2) & (N_ / 64 - 1)) * 64;
      const char* kp = Kc + (size_t)(m2 + srow) * 128 + sboff;
      kra[0] = *(const float4*)kp;  kra[1] = *(const float4*)(kp + 16);
      const char* vp = Vc + (size_t)m2 * 2 + sboff;
      vra[0] = *(const float4*)vp;  vra[1] = *(const float4*)(vp + 16);
    }
    __syncthreads();
    compute();
  }

  // epilogue: O[row][hd] / l -> Oh[b][h][n][hd] bf16
  float inv[4];
#pragma unroll
  for (int r = 0; r < 4; ++r) inv[r] = 1.0f / l[r];
  u16* __restrict__ Ob = Oh + (bh * N_ + n0 + wv * 16) * HD_;
#pragma unroll
  for (int jh = 0; jh < 4; ++jh)
#pragma unroll
    for (int r = 0; r < 4; ++r)
      Ob[(size_t)(g * 4 + r) * HD_ + jh * 16 + c] = f2bf(o[jh][r] * inv[r]);
}

// ---------------------------------------------------------------------------
extern "C" void kernel_launch(void* const* d_in, const int* in_sizes, int n_in,
                              void* d_out, int out_size, void* d_ws, size_t ws_size,
                              hipStream_t stream) {
  const float* query  = (const float*)d_in[0];
  const float* key_in = (const float*)d_in[1];
  const float* value  = (const float*)d_in[2];
  const float* Wq     = (const float*)d_in[3];
  const float* bq     = (const float*)d_in[4];
  const float* Wk     = (const float*)d_in[5];
  const float* bkb    = (const float*)d_in[6];
  const float* Wv     = (const float*)d_in[7];
  const float* bv     = (const float*)d_in[8];
  const float* Wm     = (const float*)d_in[9];
  const float* bm     = (const float*)d_in[10];
  float* out = (float*)d_out;

  const size_t Q  = (size_t)B_ * D_ * N_;   // 8.39M (== B*H*N*HD)
  const size_t WE = (size_t)D_ * D_;
  float* pb = (float*)d_ws;                  // 33.5 MB fp32 proj scratch
  u16* wqb  = (u16*)(pb + Q);
  u16* wkb  = wqb + WE;
  u16* wvb  = wkb + WE;
  u16* wmb  = wvb + WE;                      // 4 x 2.1 MB bf16 weights
  u16* xt   = wmb + WE;                      // 16.8 MB bf16 proj B-operand
  u16* qh   = xt + Q;                        // [B][H][N][64]
  u16* kh   = qh + Q;
  u16* vh   = kh + Q;                        // [B][H][64][N]
  u16* oh   = vh + Q;                        // [B][H][N][64]  (total ~126 MB)

  const dim3 blk(256);
  const dim3 wgrid(WE / (256 * 4), 1, 4);
  const dim3 tgrid(N_ / 64, D_ / 64, B_);
  const dim3 pgrid(N_ / 128, D_ / 128, B_);
  const dim3 rgrid(N_ / 64, H_, B_);
  const dim3 vgrid(N_ / 1024, D_, B_);
  const dim3 agrid(N_ / 64, H_, B_);
  const dim3 ogrid(N_, B_);

  hipLaunchKernelGGL(convert_w4, wgrid, blk, 0, stream,
                     Wq, Wk, Wv, Wm, wqb, wkb, wvb, wmb);

  hipLaunchKernelGGL(transpose_cast, tgrid, blk, 0, stream, query, xt);
  hipLaunchKernelGGL(proj_mfma, pgrid, blk, 0, stream, wqb, xt, bq, pb);
  hipLaunchKernelGGL(repack_nh, rgrid, blk, 0, stream, pb, qh);

  hipLaunchKernelGGL(transpose_cast, tgrid, blk, 0, stream, key_in, xt);
  hipLaunchKernelGGL(proj_mfma, pgrid, blk, 0, stream, wkb, xt, bkb, pb);
  hipLaunchKernelGGL(repack_nh, rgrid, blk, 0, stream, pb, kh);

  hipLaunchKernelGGL(transpose_cast, tgrid, blk, 0, stream, value, xt);
  hipLaunchKernelGGL(proj_mfma, pgrid, blk, 0, stream, wvb, xt, bv, pb);
  hipLaunchKernelGGL(repack_vh, vgrid, blk, 0, stream, pb, vh);

  hipLaunchKernelGGL(attn_mfma, agrid, blk, 0, stream, qh, kh, vh, oh);

  hipLaunchKernelGGL(repack_oh, ogrid, blk, 0, stream, oh, xt);
  hipLaunchKernelGGL(proj_mfma, pgrid, blk, 0, stream, wmb, xt, bm, out);
}

// Round 6
// 613.545 us; speedup vs baseline: 1.0597x; 1.0597x over previous
//
#include <hip/hip_runtime.h>

#define B_ 4
#define D_ 1024
#define N_ 2048
#define H_ 16
#define HD_ 64

typedef unsigned short u16;
typedef __attribute__((ext_vector_type(8))) short bf16x8;
typedef __attribute__((ext_vector_type(4))) float f32x4;
typedef __attribute__((ext_vector_type(8))) unsigned short ushort8v;
typedef __attribute__((ext_vector_type(4))) unsigned short ushort4v;

__device__ __forceinline__ u16 f2bf(float f) {
  unsigned u = __builtin_bit_cast(unsigned, f);
  u += 0x7FFFu + ((u >> 16) & 1u);   // RNE
  return (u16)(u >> 16);
}

// src channel for head-major index p (p = h*64+hd  ->  hd*16+h)
#define SRC_CH(p) ((((p) & 63) << 4) | ((p) >> 6))

// ---------------------------------------------------------------------------
// convert_w_rows: Wq/Wk/Wv [D][D] fp32 -> bf16 with ROWS permuted to
// head-major order e' = h*64+hd (source row hd*16+h). Coalesced both sides.
// ---------------------------------------------------------------------------
__global__ __launch_bounds__(256) void convert_w_rows(
    const float* __restrict__ w0, const float* __restrict__ w1,
    const float* __restrict__ w2,
    u16* __restrict__ o0, u16* __restrict__ o1, u16* __restrict__ o2) {
  const int z = blockIdx.y;
  const float* s = (z == 0) ? w0 : (z == 1) ? w1 : w2;
  u16*         o = (z == 0) ? o0 : (z == 1) ? o1 : o2;
  const int ep = blockIdx.x;            // dest row (head-major)
  const int e  = SRC_CH(ep);            // source row
  const int t4 = threadIdx.x * 4;
  const float4 v = *(const float4*)&s[(size_t)e * D_ + t4];
  ushort4v u;
  u[0] = f2bf(v.x); u[1] = f2bf(v.y); u[2] = f2bf(v.z); u[3] = f2bf(v.w);
  *(ushort4v*)&o[(size_t)ep * D_ + t4] = u;
}

// ---------------------------------------------------------------------------
// convert_w_cols: Wm [D][D] fp32 -> bf16 with COLUMNS permuted to head-major
// d' = h*64+hd (source col hd*16+h). One block per row; scattered fp32 reads
// (collectively line-covered), contiguous bf16 writes.
// ---------------------------------------------------------------------------
__global__ __launch_bounds__(256) void convert_w_cols(
    const float* __restrict__ w, u16* __restrict__ o) {
  const int e = blockIdx.x;
  const int t = threadIdx.x;
  ushort4v u;
#pragma unroll
  for (int j = 0; j < 4; ++j) {
    const int dp = t * 4 + j;
    u[j] = f2bf(w[(size_t)e * D_ + SRC_CH(dp)]);
  }
  *(ushort4v*)&o[(size_t)e * D_ + t * 4] = u;
}

// ---------------------------------------------------------------------------
// Transpose+cast: X[b][d][n] fp32 -> Xt[b][n][d] bf16 (K-contiguous B-operand).
// ---------------------------------------------------------------------------
__global__ __launch_bounds__(256) void transpose_cast(
    const float* __restrict__ X, u16* __restrict__ Xt) {
  const int b  = blockIdx.z;
  const int n0 = blockIdx.x * 64;
  const int d0 = blockIdx.y * 64;
  __shared__ float t[64][65];
  const int tid = threadIdx.x;
  const int r   = tid >> 2;
  const int cb  = (tid & 3) * 16;
  const float* __restrict__ Xb = X + (size_t)b * D_ * N_;
  u16* __restrict__ Xtb        = Xt + (size_t)b * N_ * D_;
#pragma unroll
  for (int j = 0; j < 4; ++j) {
    const float4 v = *(const float4*)&Xb[(size_t)(d0 + r) * N_ + n0 + cb + j * 4];
    t[r][cb + j * 4 + 0] = v.x;
    t[r][cb + j * 4 + 1] = v.y;
    t[r][cb + j * 4 + 2] = v.z;
    t[r][cb + j * 4 + 3] = v.w;
  }
  __syncthreads();
  ushort8v lo, hi;
#pragma unroll
  for (int j = 0; j < 8; ++j) lo[j] = f2bf(t[cb + j][r]);
#pragma unroll
  for (int j = 0; j < 8; ++j) hi[j] = f2bf(t[cb + 8 + j][r]);
  *(ushort8v*)&Xtb[(size_t)(n0 + r) * D_ + d0 + cb]     = lo;
  *(ushort8v*)&Xtb[(size_t)(n0 + r) * D_ + d0 + cb + 8] = hi;
}

// ---------------------------------------------------------------------------
// Shared main loop for all proj variants: 128x128 tile, BK=32, 4 waves 2x2,
// 4x4 frags of 16x16x32. acc[i][j] holds rows e0+wm+i*16+rg+r,
// cols n0+wn+j*16+c  (C/D: col=lane&15, row=(lane>>4)*4+reg).
// ---------------------------------------------------------------------------
#define PROJ_MAIN_LOOP(Wb, Xb)                                                \
  const int tid  = threadIdx.x;                                               \
  const int w    = tid >> 6;                                                  \
  const int lane = tid & 63;                                                  \
  const int wm   = (w >> 1) * 64;                                             \
  const int wn   = (w & 1) * 64;                                              \
  const int srow  = lane >> 2;                                                \
  const int skcol = (lane & 3) * 8;                                           \
  const int c0    = w * 2;                                                    \
  const f32x4 z4 = {0.f, 0.f, 0.f, 0.f};                                      \
  f32x4 acc[4][4];                                                            \
  _Pragma("unroll") for (int i = 0; i < 4; ++i)                               \
      _Pragma("unroll") for (int j = 0; j < 4; ++j) acc[i][j] = z4;           \
  for (int k0 = 0; k0 < D_; k0 += 32) {                                       \
    __syncthreads();                                                          \
    _Pragma("unroll") for (int i = 0; i < 2; ++i) {                           \
      const int c = c0 + i;                                                   \
      const u16* ga = Wb + (size_t)(e0 + c * 16 + srow) * D_ + k0 + skcol;    \
      const u16* gb = Xb + (size_t)(n0 + c * 16 + srow) * D_ + k0 + skcol;    \
      __builtin_amdgcn_global_load_lds(                                       \
          (__attribute__((address_space(1))) void*)ga,                        \
          (__attribute__((address_space(3))) void*)(As + c * 512), 16, 0, 0); \
      __builtin_amdgcn_global_load_lds(                                       \
          (__attribute__((address_space(1))) void*)gb,                        \
          (__attribute__((address_space(3))) void*)(Bs + c * 512), 16, 0, 0); \
    }                                                                         \
    __syncthreads();                                                          \
    bf16x8 af[4], bfr[4];                                                     \
    _Pragma("unroll") for (int i = 0; i < 4; ++i)                             \
        af[i] = *(const bf16x8*)&As[(wm + i * 16 + (lane & 15)) * 32 +        \
                                    (lane >> 4) * 8];                         \
    _Pragma("unroll") for (int j = 0; j < 4; ++j)                             \
        bfr[j] = *(const bf16x8*)&Bs[(wn + j * 16 + (lane & 15)) * 32 +       \
                                     (lane >> 4) * 8];                        \
    _Pragma("unroll") for (int i = 0; i < 4; ++i)                             \
        _Pragma("unroll") for (int j = 0; j < 4; ++j)                         \
            acc[i][j] = __builtin_amdgcn_mfma_f32_16x16x32_bf16(              \
                af[i], bfr[j], acc[i][j], 0, 0, 0);                           \
  }

// ---------------------------------------------------------------------------
// proj_mfma: fp32 output [B][D][N] (final m-projection). Scattered dword
// stores -- empirically benign in R3 (fp32 segments merge in L2).
// ---------------------------------------------------------------------------
__global__ __launch_bounds__(256) void proj_mfma(
    const u16* __restrict__ Wb, const u16* __restrict__ Xt,
    const float* __restrict__ bias, float* __restrict__ Y) {
  const int b  = blockIdx.z;
  const int n0 = blockIdx.x * 128;
  const int e0 = blockIdx.y * 128;
  const u16* __restrict__ Xb = Xt + (size_t)b * N_ * D_;
  float* __restrict__ Yb     = Y + (size_t)b * D_ * N_;
  __shared__ __attribute__((aligned(16))) u16 As[128 * 32];
  __shared__ __attribute__((aligned(16))) u16 Bs[128 * 32];
  PROJ_MAIN_LOOP(Wb, Xb)
  const int col = lane & 15;
  const int rg  = (lane >> 4) * 4;
#pragma unroll
  for (int i = 0; i < 4; ++i) {
#pragma unroll
    for (int r = 0; r < 4; ++r) {
      const int e    = e0 + wm + i * 16 + rg + r;
      const float be = bias[e];
      float* yr = &Yb[(size_t)e * N_ + n0 + wn + col];
#pragma unroll
      for (int j = 0; j < 4; ++j) yr[j * 16] = acc[i][j][r] + be;
    }
  }
}

// ---------------------------------------------------------------------------
// proj_mfma_qk: ROW-permuted head-major weights; tile rows cover heads
// 2*blockIdx.y (+1). Epilogue: per head-half, stage [hd][n] in LDS, store
// TRANSPOSED [b][h][n][hd] bf16 with full-128B-line coalescing.
// ---------------------------------------------------------------------------
__global__ __launch_bounds__(256) void proj_mfma_qk(
    const u16* __restrict__ Wb, const u16* __restrict__ Xt,
    const float* __restrict__ bias, u16* __restrict__ Qout) {
  const int b  = blockIdx.z;
  const int n0 = blockIdx.x * 128;
  const int e0 = blockIdx.y * 128;
  const u16* __restrict__ Xb = Xt + (size_t)b * N_ * D_;
  __shared__ __attribute__((aligned(16))) u16 SH[64 * 132];  // >= 2*4096
  u16* As = SH;
  u16* Bs = SH + 4096;
  PROJ_MAIN_LOOP(Wb, Xb)
  const int col = lane & 15;
  const int rg  = (lane >> 4) * 4;
  const int h0  = blockIdx.y * 2;
#pragma unroll
  for (int eh = 0; eh < 2; ++eh) {
    __syncthreads();                    // prior SH use (staging / prev read) done
    if ((w >> 1) == eh) {               // the 2 waves owning this half
#pragma unroll
      for (int i = 0; i < 4; ++i) {
#pragma unroll
        for (int r = 0; r < 4; ++r) {
          const int el = i * 16 + rg + r;             // hd 0..63
          const int ep = e0 + eh * 64 + el;           // head-major channel
          const float be = bias[SRC_CH(ep)];
#pragma unroll
          for (int j = 0; j < 4; ++j)
            SH[el * 132 + wn + j * 16 + col] = f2bf(acc[i][j][r] + be);
        }
      }
    }
    __syncthreads();
    // store transposed: thread t -> row n = t>>1, 32-hd chunk (t&1); 64 B each,
    // 2 threads per full 128 B line of Qout.
    const int nn = tid >> 1;
    const int hc = (tid & 1) * 32;
    u16* dst = Qout + (((size_t)(b * H_ + h0 + eh) * N_) + n0 + nn) * HD_ + hc;
#pragma unroll
    for (int q = 0; q < 4; ++q) {
      ushort8v pk;
#pragma unroll
      for (int x = 0; x < 8; ++x) pk[x] = SH[(hc + q * 8 + x) * 132 + nn];
      *(ushort8v*)(dst + q * 8) = pk;
    }
  }
}

// ---------------------------------------------------------------------------
// proj_mfma_v: ROW-permuted head-major weights -> Vout[b][h][hd][n] bf16.
// R5-audit fix: scattered per-lane u16 stores (R3's measured 63x write-
// amplification pattern) replaced by LDS-staged 64B-contiguous stores.
// Row stride 136 u16 keeps the ds_read_b128 16B-aligned.
// ---------------------------------------------------------------------------
__global__ __launch_bounds__(256) void proj_mfma_v(
    const u16* __restrict__ Wb, const u16* __restrict__ Xt,
    const float* __restrict__ bias, u16* __restrict__ Vout) {
  const int b  = blockIdx.z;
  const int n0 = blockIdx.x * 128;
  const int e0 = blockIdx.y * 128;
  const u16* __restrict__ Xb = Xt + (size_t)b * N_ * D_;
  __shared__ __attribute__((aligned(16))) u16 SH[64 * 136];  // >= 2*4096
  u16* As = SH;
  u16* Bs = SH + 4096;
  PROJ_MAIN_LOOP(Wb, Xb)
  const int col = lane & 15;
  const int rg  = (lane >> 4) * 4;
#pragma unroll
  for (int eh = 0; eh < 2; ++eh) {
    __syncthreads();                    // prior SH use done
    if ((w >> 1) == eh) {               // the 2 waves owning this row-half
#pragma unroll
      for (int i = 0; i < 4; ++i) {
#pragma unroll
        for (int r = 0; r < 4; ++r) {
          const int el = i * 16 + rg + r;             // 0..63
          const int ep = e0 + eh * 64 + el;           // head-major channel
          const float be = bias[SRC_CH(ep)];
#pragma unroll
          for (int j = 0; j < 4; ++j)
            SH[el * 136 + wn + j * 16 + col] = f2bf(acc[i][j][r] + be);
        }
      }
    }
    __syncthreads();
    // coalesced row-major store: thread t -> row el = t>>2, 64B chunk (t&3).
    const int el = tid >> 2;
    const int nc = (tid & 3) * 32;
    const int ep = e0 + eh * 64 + el;
    u16* dst = Vout + (((size_t)(b * H_ + (ep >> 6)) * HD_ + (ep & 63)) * N_)
               + n0 + nc;
    const u16* src = &SH[el * 136 + nc];
#pragma unroll
    for (int q = 0; q < 4; ++q)
      *(ushort8v*)(dst + q * 8) = *(const ushort8v*)(src + q * 8);
  }
}

// ---------------------------------------------------------------------------
// repack_oh2: Oh[b][h][n][hd] bf16 -> Xt[b][n][d'=h*64+hd] bf16.
// Pure 16B-chunk copy, coalesced both sides (d' is head-major).
// ---------------------------------------------------------------------------
__global__ __launch_bounds__(256) void repack_oh2(
    const u16* __restrict__ Oh, u16* __restrict__ Xt) {
  const size_t F = ((size_t)blockIdx.x * 256 + threadIdx.x) * 8;
  const int b  = (int)(F >> 21);          // / (N_*1024)
  const int n  = (int)(F >> 10) & (N_ - 1);
  const int dp = (int)F & 1023;
  const int h  = dp >> 6;
  const int hd = dp & 63;
  *(ushort8v*)&Xt[F] =
      *(const ushort8v*)&Oh[(((size_t)(b * H_ + h) * N_) + n) * HD_ + hd];
}

// ---------------------------------------------------------------------------
// attn_mfma: XCD-clustered grid, coalesced LDS-staged epilogue.
// Qh/Kh: [B][H][N][64]; Vh: [B][H][64][N]; Oh: [B][H][N][64].
// ---------------------------------------------------------------------------
__global__ __launch_bounds__(256) void attn_mfma(
    const u16* __restrict__ Qh, const u16* __restrict__ Kh,
    const u16* __restrict__ Vh, u16* __restrict__ Oh) {
  const int hw  = blockIdx.x;
  const int xcd = hw & 7;
  const int idx = hw >> 3;
  const int grp = xcd * 8 + (idx >> 5);
  const int til = idx & 31;
  const int n0  = til * 64;
  const int b   = grp >> 4;
  const int h   = grp & 15;

  const int tid  = threadIdx.x;
  const int wv   = tid >> 6;
  const int lane = tid & 63;
  const int g    = lane >> 4;
  const int c    = lane & 15;

  __shared__ __attribute__((aligned(16))) u16 Ks[64 * 72];
  __shared__ __attribute__((aligned(16))) u16 Vs[64 * 72];
  __shared__ __attribute__((aligned(16))) u16 ps[4][16 * 72];

  const size_t bh = (size_t)(b * H_ + h);
  const u16* __restrict__ Qbase = Qh + bh * N_ * HD_;
  const char* __restrict__ Kc   = (const char*)(Kh + bh * N_ * HD_);
  const char* __restrict__ Vc0  = (const char*)(Vh + bh * HD_ * N_);

  bf16x8 qa[2];
  {
    const u16* qrow = Qbase + (size_t)(n0 + wv * 16 + c) * HD_ + g * 8;
    qa[0] = *(const bf16x8*)(qrow);
    qa[1] = *(const bf16x8*)(qrow + 32);
  }

  const int srow  = tid >> 2;
  const int sboff = (tid & 3) * 32;
  const char* Vc = Vc0 + (size_t)srow * (N_ * 2);
  u16* KsW = Ks + srow * 72 + sboff / 2;
  u16* VsW = Vs + srow * 72 + sboff / 2;

  f32x4 o[4];
  float mold[4], l[4];
#pragma unroll
  for (int jh = 0; jh < 4; ++jh) o[jh] = f32x4{0.f, 0.f, 0.f, 0.f};
#pragma unroll
  for (int r = 0; r < 4; ++r) { mold[r] = -1e30f; l[r] = 0.f; }

  const float sc = 0.125f;

  auto compute = [&]() {
    f32x4 s[4];
#pragma unroll
    for (int j = 0; j < 4; ++j) s[j] = f32x4{0.f, 0.f, 0.f, 0.f};
#pragma unroll
    for (int ks = 0; ks < 2; ++ks) {
#pragma unroll
      for (int j = 0; j < 4; ++j) {
        const bf16x8 kb = *(const bf16x8*)&Ks[(j * 16 + c) * 72 + ks * 32 + g * 8];
        s[j] = __builtin_amdgcn_mfma_f32_16x16x32_bf16(qa[ks], kb, s[j], 0, 0, 0);
      }
    }
#pragma unroll
    for (int r = 0; r < 4; ++r) {
      float m_ = fmaxf(fmaxf(s[0][r], s[1][r]), fmaxf(s[2][r], s[3][r])) * sc;
      m_ = fmaxf(m_, __shfl_xor(m_, 1));
      m_ = fmaxf(m_, __shfl_xor(m_, 2));
      m_ = fmaxf(m_, __shfl_xor(m_, 4));
      m_ = fmaxf(m_, __shfl_xor(m_, 8));
      const float mnew = fmaxf(mold[r], m_);
      const float al   = __expf(mold[r] - mnew);
      mold[r] = mnew;
      float ls = 0.f;
#pragma unroll
      for (int j = 0; j < 4; ++j) {
        const float p = __expf(s[j][r] * sc - mnew);
        ps[wv][(g * 4 + r) * 72 + j * 16 + c] = f2bf(p);
        ls += p;
      }
      ls += __shfl_xor(ls, 1);
      ls += __shfl_xor(ls, 2);
      ls += __shfl_xor(ls, 4);
      ls += __shfl_xor(ls, 8);
      l[r] = l[r] * al + ls;
      o[0][r] *= al; o[1][r] *= al; o[2][r] *= al; o[3][r] *= al;
    }
#pragma unroll
    for (int ks = 0; ks < 2; ++ks) {
      const bf16x8 pa = *(const bf16x8*)&ps[wv][c * 72 + ks * 32 + g * 8];
#pragma unroll
      for (int jh = 0; jh < 4; ++jh) {
        const bf16x8 vb = *(const bf16x8*)&Vs[(jh * 16 + c) * 72 + ks * 32 + g * 8];
        o[jh] = __builtin_amdgcn_mfma_f32_16x16x32_bf16(pa, vb, o[jh], 0, 0, 0);
      }
    }
  };

  float4 kra[2], vra[2], krb[2], vrb[2];
  {
    const char* kp = Kc + (size_t)srow * 128 + sboff;
    kra[0] = *(const float4*)kp;  kra[1] = *(const float4*)(kp + 16);
    const char* vp = Vc + sboff;
    vra[0] = *(const float4*)vp;  vra[1] = *(const float4*)(vp + 16);
  }

  for (int t = 0; t < N_ / 64; t += 2) {
    __syncthreads();
    *(float4*)(KsW) = kra[0];  *(float4*)(KsW + 8) = kra[1];
    *(float4*)(VsW) = vra[0];  *(float4*)(VsW + 8) = vra[1];
    {
      const int m1 = (t + 1) * 64;
      const char* kp = Kc + (size_t)(m1 + srow) * 128 + sboff;
      krb[0] = *(const float4*)kp;  krb[1] = *(const float4*)(kp + 16);
      const char* vp = Vc + (size_t)m1 * 2 + sboff;
      vrb[0] = *(const float4*)vp;  vrb[1] = *(const float4*)(vp + 16);
    }
    __syncthreads();
    compute();
    __syncthreads();
    *(float4*)(KsW) = krb[0];  *(float4*)(KsW + 8) = krb[1];
    *(float4*)(VsW) = vrb[0];  *(float4*)(VsW + 8) = vrb[1];
    {
      const int m2 = ((t + 2) & (N_ / 64 - 1)) * 64;
      const char* kp = Kc + (size_t)(m2 + srow) * 128 + sboff;
      kra[0] = *(const float4*)kp;  kra[1] = *(const float4*)(kp + 16);
      const char* vp = Vc + (size_t)m2 * 2 + sboff;
      vra[0] = *(const float4*)vp;  vra[1] = *(const float4*)(vp + 16);
    }
    __syncthreads();
    compute();
  }

  float inv[4];
#pragma unroll
  for (int r = 0; r < 4; ++r) inv[r] = 1.0f / l[r];
#pragma unroll
  for (int jh = 0; jh < 4; ++jh)
#pragma unroll
    for (int r = 0; r < 4; ++r)
      ps[wv][(g * 4 + r) * 72 + jh * 16 + c] = f2bf(o[jh][r] * inv[r]);

  const int orow = lane >> 2;
  const int och  = (lane & 3) * 16;
  const u16* osrc = &ps[wv][orow * 72 + och];
  u16* odst = Oh + (bh * N_ + n0 + wv * 16 + orow) * HD_ + och;
  *(ushort8v*)odst       = *(const ushort8v*)osrc;
  *(ushort8v*)(odst + 8) = *(const ushort8v*)(osrc + 8);
}

// ---------------------------------------------------------------------------
extern "C" void kernel_launch(void* const* d_in, const int* in_sizes, int n_in,
                              void* d_out, int out_size, void* d_ws, size_t ws_size,
                              hipStream_t stream) {
  const float* query  = (const float*)d_in[0];
  const float* key_in = (const float*)d_in[1];
  const float* value  = (const float*)d_in[2];
  const float* Wq     = (const float*)d_in[3];
  const float* bq     = (const float*)d_in[4];
  const float* Wk     = (const float*)d_in[5];
  const float* bkb    = (const float*)d_in[6];
  const float* Wv     = (const float*)d_in[7];
  const float* bv     = (const float*)d_in[8];
  const float* Wm     = (const float*)d_in[9];
  const float* bm     = (const float*)d_in[10];
  float* out = (float*)d_out;

  const size_t Q  = (size_t)B_ * D_ * N_;
  const size_t WE = (size_t)D_ * D_;
  u16* wqb = (u16*)d_ws;
  u16* wkb = wqb + WE;
  u16* wvb = wkb + WE;
  u16* wmb = wvb + WE;          // 4 x 2.1 MB bf16 weights
  u16* xt  = wmb + WE;          // 16.8 MB proj B-operand
  u16* qh  = xt + Q;            // [B][H][N][64]
  u16* kh  = qh + Q;
  u16* vh  = kh + Q;            // [B][H][64][N]
  u16* oh  = vh + Q;            // [B][H][N][64]   total ~92 MB

  const dim3 blk(256);
  const dim3 wrgrid(D_, 3);
  const dim3 wcgrid(D_);
  const dim3 tgrid(N_ / 64, D_ / 64, B_);
  const dim3 pgrid(N_ / 128, D_ / 128, B_);
  const dim3 agrid(B_ * H_ * (N_ / 64));     // 2048, XCD-clustered
  const dim3 o2grid(Q / (256 * 8));          // 4096

  hipLaunchKernelGGL(convert_w_rows, wrgrid, blk, 0, stream,
                     Wq, Wk, Wv, wqb, wkb, wvb);
  hipLaunchKernelGGL(convert_w_cols, wcgrid, blk, 0, stream, Wm, wmb);

  hipLaunchKernelGGL(transpose_cast, tgrid, blk, 0, stream, query, xt);
  hipLaunchKernelGGL(proj_mfma_qk, pgrid, blk, 0, stream, wqb, xt, bq, qh);

  hipLaunchKernelGGL(transpose_cast, tgrid, blk, 0, stream, key_in, xt);
  hipLaunchKernelGGL(proj_mfma_qk, pgrid, blk, 0, stream, wkb, xt, bkb, kh);

  hipLaunchKernelGGL(transpose_cast, tgrid, blk, 0, stream, value, xt);
  hipLaunchKernelGGL(proj_mfma_v, pgrid, blk, 0, stream, wvb, xt, bv, vh);

  hipLaunchKernelGGL(attn_mfma, agrid, blk, 0, stream, qh, kh, vh, oh);

  hipLaunchKernelGGL(repack_oh2, o2grid, blk, 0, stream, oh, xt);
  hipLaunchKernelGGL(proj_mfma, pgrid, blk, 0, stream, wmb, xt, bm, out);
}